// Round 2
// baseline (11.774 us; speedup 1.0000x reference)
//
#include <hip/hip_runtime.h>

// Ragged gather: out[cu[i] + p] = req_to_token[req_pool_indices[i]][chunk_starts[i] + p]
// for p in [0, chunk_seq_lens[i]), i in [0, BATCH).
//
// Inputs (setup_inputs order):
//  d_in[0] req_to_token      int32 [4096, 32768]
//  d_in[1] req_pool_indices  int32 [BATCH]
//  d_in[2] chunk_starts      int32 [BATCH]
//  d_in[3] chunk_seq_lens    int32 [BATCH]
//  d_in[4] chunk_cu_seq_lens int32 [BATCH+1]
//  d_in[5] num_chunk_tokens  int32 [1]
// Output: int32 [T]
//
// MAX_CHUNK = 4096 (reference guarantees chunk_seq_lens <= 4096), so
// grid (BATCH, 4) x 256 threads x 4 elems/thread = 4096 covers any request
// without a grid-stride loop.

#define MAX_CONTEXT 32768

__global__ void ragged_gather_v2(const int* __restrict__ req_to_token,
                                 const int* __restrict__ req_pool_indices,
                                 const int* __restrict__ chunk_starts,
                                 const int* __restrict__ chunk_cu,
                                 int* __restrict__ out) {
    const int req   = blockIdx.x;
    const int begin = chunk_cu[req];
    const int len   = chunk_cu[req + 1] - begin;

    const int p0 = (threadIdx.x + blockIdx.y * blockDim.x) * 4;
    if (p0 >= len) return;

    const int* __restrict__ src =
        req_to_token + (size_t)req_pool_indices[req] * (size_t)MAX_CONTEXT
                     + chunk_starts[req];
    int* __restrict__ dst = out + begin;

    if (p0 + 4 <= len) {
        // Full quad: 4 pipelined dword loads (one latency, 4 elements).
        int a = src[p0];
        int b = src[p0 + 1];
        int c = src[p0 + 2];
        int d = src[p0 + 3];
        dst[p0]     = a;
        dst[p0 + 1] = b;
        dst[p0 + 2] = c;
        dst[p0 + 3] = d;
    } else {
        // Ragged tail of the request (at most one thread per request).
        for (int p = p0; p < len; ++p) dst[p] = src[p];
    }
}

extern "C" void kernel_launch(void* const* d_in, const int* in_sizes, int n_in,
                              void* d_out, int out_size, void* d_ws, size_t ws_size,
                              hipStream_t stream) {
    const int* req_to_token     = (const int*)d_in[0];
    const int* req_pool_indices = (const int*)d_in[1];
    const int* chunk_starts     = (const int*)d_in[2];
    const int* chunk_cu         = (const int*)d_in[4];
    int*       out              = (int*)d_out;

    const int batch = in_sizes[1];  // 64

    dim3 grid(batch, 4, 1);   // 256 blocks; 4 blocks x 256 thr x 4 elems = 4096/request
    dim3 block(256, 1, 1);
    ragged_gather_v2<<<grid, block, 0, stream>>>(
        req_to_token, req_pool_indices, chunk_starts, chunk_cu, out);
}

// Round 3
// 9.721 us; speedup vs baseline: 1.2113x; 1.2113x over previous
//
#include <hip/hip_runtime.h>

// Ragged gather: out[cu[i] + p] = req_to_token[req_pool_indices[i]][chunk_starts[i] + p]
// for p in [0, chunk_seq_lens[i]), i in [0, BATCH).
//
// Inputs (setup_inputs order):
//  d_in[0] req_to_token      int32 [4096, 32768]
//  d_in[1] req_pool_indices  int32 [BATCH]
//  d_in[2] chunk_starts      int32 [BATCH]
//  d_in[3] chunk_seq_lens    int32 [BATCH]
//  d_in[4] chunk_cu_seq_lens int32 [BATCH+1]
//  d_in[5] num_chunk_tokens  int32 [1]
// Output: int32 [T]
//
// Latency-bound regime (total traffic ~1 MB): one element per thread,
// no loop. grid (BATCH, 16) x 256 threads = 4096 threads/request covers
// MAX_CHUNK=4096 with a single predicated load+store.

#define MAX_CONTEXT 32768

__global__ void ragged_gather_v3(const int* __restrict__ req_to_token,
                                 const int* __restrict__ req_pool_indices,
                                 const int* __restrict__ chunk_starts,
                                 const int* __restrict__ chunk_cu,
                                 int* __restrict__ out) {
    const int req   = blockIdx.x;
    const int begin = chunk_cu[req];          // scalar (wave-uniform) loads
    const int len   = chunk_cu[req + 1] - begin;

    const int p = threadIdx.x + blockIdx.y * blockDim.x;
    if (p >= len) return;

    const int* __restrict__ src =
        req_to_token + (size_t)req_pool_indices[req] * (size_t)MAX_CONTEXT
                     + chunk_starts[req];
    out[begin + p] = src[p];                  // 1 load + 1 store per thread
}

extern "C" void kernel_launch(void* const* d_in, const int* in_sizes, int n_in,
                              void* d_out, int out_size, void* d_ws, size_t ws_size,
                              hipStream_t stream) {
    const int* req_to_token     = (const int*)d_in[0];
    const int* req_pool_indices = (const int*)d_in[1];
    const int* chunk_starts     = (const int*)d_in[2];
    const int* chunk_cu         = (const int*)d_in[4];
    int*       out              = (int*)d_out;

    const int batch = in_sizes[1];  // 64

    dim3 grid(batch, 16, 1);   // 1024 blocks; 16 x 256 = 4096 threads/request
    dim3 block(256, 1, 1);
    ragged_gather_v3<<<grid, block, 0, stream>>>(
        req_to_token, req_pool_indices, chunk_starts, chunk_cu, out);
}